// Round 4
// baseline (302.391 us; speedup 1.0000x reference)
//
#include <hip/hip_runtime.h>

// TopKActivation: out = relu(x) masked to the row-wise top-k of relu(x).
// [16384 x 4096] fp32, k=64. One 256-thread block per row, 16 elem/thread in
// registers. Latency hiding comes from block-level TLP (8 blocks/CU via
// __launch_bounds__(256,8)) — explicit software pipelining measured WORSE
// (R3: spills + lost TLP, 214us vs 120us).
//
// Threshold: candidates > 1.5f compacted into LDS (~274 of 4096 for N(0,1));
// wave 0 alone runs a 4x8-bit MSB radix select on the compacted list
// (positive floats order as uints). Only 4 block barriers on the fast path.
// Exact full-block fallback if the prefilter fails (cnt < k or cnt > CAP).
// Ties at the threshold resolved stably (lowest column index first) to match
// XLA top_k. Loads are temporal (input ~fits L3, stays resident across graph
// replays); stores are nontemporal (don't evict the input with output lines).

constexpr int ROW_LEN = 4096;
constexpr int TPB     = 256;
constexpr int EPT     = ROW_LEN / TPB; // 16
constexpr int CAP     = 512;
constexpr unsigned int KPRE_BITS = 0x3FC00000u; // bits of 1.5f

typedef float f32x4 __attribute__((ext_vector_type(4)));

__global__ __launch_bounds__(TPB, 8)
void topk_relu_kernel(const float* __restrict__ x, const int* __restrict__ kptr,
                      float* __restrict__ out, int rows)
{
    __shared__ unsigned int cand[CAP];
    __shared__ alignas(16) int hist[256];
    __shared__ int ccount;
    __shared__ unsigned int selT;
    __shared__ int selNeed;
    __shared__ int wtot[4];
    __shared__ int sel_digit, sel_kk, sel_flag;

    const int row = blockIdx.x;
    if (row >= rows) return;
    const int tid  = threadIdx.x;
    const int lane = tid & 63;
    const int wid  = tid >> 6;

    int k = *kptr;
    if (k > ROW_LEN) k = ROW_LEN;

    // ---- load row (blocked: thread t owns cols [16t,16t+16) => thread order == col order) ----
    const size_t rowbase = (size_t)row * ROW_LEN + (size_t)tid * EPT;
    const f32x4* __restrict__ xv = (const f32x4*)(x + rowbase);
    unsigned int key[EPT];
#pragma unroll
    for (int j = 0; j < 4; ++j) {
        f32x4 v = xv[j]; // temporal: let input stay L3-resident across replays
#pragma unroll
        for (int c = 0; c < 4; ++c)
            key[4 * j + c] = __float_as_uint(fmaxf(v[c], 0.0f));
    }

    if (tid == 0) ccount = 0;
    __syncthreads(); // B1

    // ---- compact candidates > 1.5f into LDS ----
    int m = 0;
#pragma unroll
    for (int j = 0; j < EPT; ++j) m += (key[j] > KPRE_BITS) ? 1 : 0;
    int inc = m;
#pragma unroll
    for (int d = 1; d < 64; d <<= 1) {
        int v = __shfl_up(inc, d);
        if (lane >= d) inc += v;
    }
    const int excl = inc - m;
    const int wt   = __shfl(inc, 63);
    int wb = 0;
    if (lane == 0) wb = atomicAdd(&ccount, wt);
    wb = __shfl(wb, 0);
    int pos = wb + excl;
#pragma unroll
    for (int j = 0; j < EPT; ++j) {
        if (key[j] > KPRE_BITS) {
            if (pos < CAP) cand[pos] = key[j];
            ++pos;
        }
    }
    __syncthreads(); // B2
    const int cnt = ccount;

    unsigned int T;
    int need;

    if (cnt >= k && cnt <= CAP) {
        // ---- fast select: wave 0 only, no intra-pass barriers ----
        if (wid == 0) {
            unsigned int c[CAP / 64];
#pragma unroll
            for (int i = 0; i < CAP / 64; ++i) {
                const int idx = lane + 64 * i;
                c[i] = (idx < cnt) ? cand[idx] : 0u;
            }
            int kk = k;
            unsigned int prefix = 0;
#pragma unroll
            for (int p = 0; p < 4; ++p) {
                const int shift = 24 - 8 * p;
                ((int4*)hist)[lane] = make_int4(0, 0, 0, 0);
#pragma unroll
                for (int i = 0; i < CAP / 64; ++i) {
                    const int idx = lane + 64 * i;
                    const unsigned int ci = c[i];
                    if (idx < cnt && (p == 0 || (ci >> (shift + 8)) == prefix))
                        atomicAdd(&hist[(ci >> shift) & 255u], 1);
                }
                const int4 h = ((const int4*)hist)[lane];
                const int h0 = h.x, h1 = h.y, h2 = h.z, h3 = h.w;
                const int lsum = h0 + h1 + h2 + h3;
                int suf = lsum; // inclusive suffix sum across lanes
#pragma unroll
                for (int d = 1; d < 64; d <<= 1) {
                    int v = __shfl_down(suf, d);
                    if (lane < 64 - d) suf += v;
                }
                const unsigned long long mm = __ballot(suf >= kk); // nonzero since cnt>=kk
                const int L = 63 - __clzll(mm);
                int dig = 0, kkn = 0;
                if (lane == L) {
                    int cum = suf - lsum;
                    const int hh[4] = {h0, h1, h2, h3};
#pragma unroll
                    for (int b = 3; b >= 0; --b) {
                        if (cum + hh[b] >= kk) { dig = lane * 4 + b; kkn = kk - cum; break; }
                        cum += hh[b];
                    }
                }
                dig = __shfl(dig, L);
                kk  = __shfl(kkn, L);
                prefix = (prefix << 8) | (unsigned int)dig;
            }
            if (lane == 0) { selT = prefix; selNeed = kk; }
        }
        __syncthreads(); // B3
        T = selT;
        need = selNeed;
    } else {
        // ---- exact fallback: full-block 4-pass histogram over all positives ----
        int kk = k;
        unsigned int prefix = 0;
        int t0 = 0;
        for (int p = 0; p < 4; ++p) {
            const int shift = 24 - 8 * p;
            hist[tid] = 0;
            if (tid == 0) sel_flag = 0;
            __syncthreads();
#pragma unroll
            for (int j = 0; j < EPT; ++j) {
                const unsigned int kj = key[j];
                if (kj != 0u && (p == 0 || (kj >> (shift + 8)) == prefix))
                    atomicAdd(&hist[(kj >> shift) & 255u], 1);
            }
            __syncthreads();
            if (tid < 64) {
                const int b0 = tid * 4;
                const int h0 = hist[b0 + 0], h1 = hist[b0 + 1];
                const int h2 = hist[b0 + 2], h3 = hist[b0 + 3];
                const int lsum = h0 + h1 + h2 + h3;
                int suf = lsum;
#pragma unroll
                for (int d = 1; d < 64; d <<= 1) {
                    int v = __shfl_down(suf, d);
                    if (lane < 64 - d) suf += v;
                }
                const unsigned long long mm = __ballot(suf >= kk);
                if (mm == 0ull) {
                    if (lane == 0) sel_flag = 1;
                } else {
                    const int L = 63 - __clzll(mm);
                    if (lane == L) {
                        int cum = suf - lsum;
                        const int hh[4] = {h0, h1, h2, h3};
#pragma unroll
                        for (int b = 3; b >= 0; --b) {
                            if (cum + hh[b] >= kk) { sel_digit = b0 + b; sel_kk = kk - cum; break; }
                            cum += hh[b];
                        }
                    }
                }
            }
            __syncthreads();
            if (sel_flag) { t0 = 1; break; }
            prefix = (prefix << 8) | (unsigned int)sel_digit;
            kk = sel_kk;
            __syncthreads(); // protect sel_* from next pass's re-init
        }
        if (t0) { T = 0u; need = 0; }
        else    { T = prefix; need = kk; }
    }

    // ---- stable rank of ==T elements in ascending column order ----
    int eqc = 0;
#pragma unroll
    for (int j = 0; j < EPT; ++j) eqc += (key[j] == T) ? 1 : 0;
    int einc = eqc;
#pragma unroll
    for (int d = 1; d < 64; d <<= 1) {
        int v = __shfl_up(einc, d);
        if (lane >= d) einc += v;
    }
    if (lane == 63) wtot[wid] = einc;
    __syncthreads(); // B4
    int rbase = 0;
    for (int w = 0; w < wid; ++w) rbase += wtot[w];
    int rr = rbase + (einc - eqc);

    // ---- emit (nontemporal: don't evict the L3-resident input) ----
    f32x4* __restrict__ ov = (f32x4*)(out + rowbase);
#pragma unroll
    for (int j = 0; j < 4; ++j) {
        f32x4 v;
#pragma unroll
        for (int c2 = 0; c2 < 4; ++c2) {
            const unsigned int kj = key[4 * j + c2];
            const bool eq = (kj == T);
            const bool keep = (kj > T) || (eq && rr < need);
            v[c2] = keep ? __uint_as_float(kj) : 0.0f;
            rr += eq ? 1 : 0;
        }
        __builtin_nontemporal_store(v, &ov[j]);
    }
}

extern "C" void kernel_launch(void* const* d_in, const int* in_sizes, int n_in,
                              void* d_out, int out_size, void* d_ws, size_t ws_size,
                              hipStream_t stream)
{
    const float* x    = (const float*)d_in[0];
    const int*   kptr = (const int*)d_in[1];
    float*       out  = (float*)d_out;
    const int rows = in_sizes[0] / ROW_LEN;
    topk_relu_kernel<<<rows, TPB, 0, stream>>>(x, kptr, out, rows);
}

// Round 5
// 214.972 us; speedup vs baseline: 1.4067x; 1.4067x over previous
//
#include <hip/hip_runtime.h>

// TopKActivation: out = relu(x) masked to the row-wise top-k of relu(x).
// [16384 x 4096] fp32, k=64. One 256-thread block per row, 16 elem/thread in
// registers. Latency hiding via block-level TLP at 4 blocks/CU.
// LESSON (R3/R4): launch_bounds(256,8) caps waves at 64 VGPR -> key[16]
// spills to scratch -> +390MB write traffic, 2.5x slower. Keep (256,4).
//
// Threshold: candidates > 1.5f compacted into LDS (~274 of 4096 for N(0,1));
// wave 0 alone runs a 4x8-bit MSB radix select on the compacted list
// (positive floats order as uints). Only 4 block barriers on the fast path.
// Exact full-block fallback if the prefilter fails (cnt < k or cnt > CAP).
// Ties at the threshold resolved stably (lowest column index first) to match
// XLA top_k. Loads temporal (input stays L3-resident across graph replays —
// measured FETCH 131MB < 268MB ideal); stores nontemporal.

constexpr int ROW_LEN = 4096;
constexpr int TPB     = 256;
constexpr int EPT     = ROW_LEN / TPB; // 16
constexpr int CAP     = 512;
constexpr unsigned int KPRE_BITS = 0x3FC00000u; // bits of 1.5f

typedef float f32x4 __attribute__((ext_vector_type(4)));

__global__ __launch_bounds__(TPB, 4)
void topk_relu_kernel(const float* __restrict__ x, const int* __restrict__ kptr,
                      float* __restrict__ out, int rows)
{
    __shared__ unsigned int cand[CAP];
    __shared__ alignas(16) int hist[256];
    __shared__ int ccount;
    __shared__ unsigned int selT;
    __shared__ int selNeed;
    __shared__ int wtot[4];
    __shared__ int sel_digit, sel_kk, sel_flag;

    const int row = blockIdx.x;
    if (row >= rows) return;
    const int tid  = threadIdx.x;
    const int lane = tid & 63;
    const int wid  = tid >> 6;

    int k = *kptr;
    if (k > ROW_LEN) k = ROW_LEN;

    // ---- load row (blocked: thread t owns cols [16t,16t+16) => thread order == col order) ----
    const size_t rowbase = (size_t)row * ROW_LEN + (size_t)tid * EPT;
    const f32x4* __restrict__ xv = (const f32x4*)(x + rowbase);
    unsigned int key[EPT];
#pragma unroll
    for (int j = 0; j < 4; ++j) {
        f32x4 v = xv[j]; // temporal: input stays L3-resident across replays
#pragma unroll
        for (int c = 0; c < 4; ++c)
            key[4 * j + c] = __float_as_uint(fmaxf(v[c], 0.0f));
    }

    if (tid == 0) ccount = 0;
    __syncthreads(); // B1

    // ---- compact candidates > 1.5f into LDS ----
    int m = 0;
#pragma unroll
    for (int j = 0; j < EPT; ++j) m += (key[j] > KPRE_BITS) ? 1 : 0;
    int inc = m;
#pragma unroll
    for (int d = 1; d < 64; d <<= 1) {
        int v = __shfl_up(inc, d);
        if (lane >= d) inc += v;
    }
    const int excl = inc - m;
    const int wt   = __shfl(inc, 63);
    int wb = 0;
    if (lane == 0) wb = atomicAdd(&ccount, wt);
    wb = __shfl(wb, 0);
    int pos = wb + excl;
#pragma unroll
    for (int j = 0; j < EPT; ++j) {
        if (key[j] > KPRE_BITS) {
            if (pos < CAP) cand[pos] = key[j];
            ++pos;
        }
    }
    __syncthreads(); // B2
    const int cnt = ccount;

    unsigned int T;
    int need;

    if (cnt >= k && cnt <= CAP) {
        // ---- fast select: wave 0 only, no intra-pass barriers ----
        if (wid == 0) {
            unsigned int c[CAP / 64];
#pragma unroll
            for (int i = 0; i < CAP / 64; ++i) {
                const int idx = lane + 64 * i;
                c[i] = (idx < cnt) ? cand[idx] : 0u;
            }
            int kk = k;
            unsigned int prefix = 0;
#pragma unroll
            for (int p = 0; p < 4; ++p) {
                const int shift = 24 - 8 * p;
                ((int4*)hist)[lane] = make_int4(0, 0, 0, 0);
#pragma unroll
                for (int i = 0; i < CAP / 64; ++i) {
                    const int idx = lane + 64 * i;
                    const unsigned int ci = c[i];
                    if (idx < cnt && (p == 0 || (ci >> (shift + 8)) == prefix))
                        atomicAdd(&hist[(ci >> shift) & 255u], 1);
                }
                const int4 h = ((const int4*)hist)[lane];
                const int h0 = h.x, h1 = h.y, h2 = h.z, h3 = h.w;
                const int lsum = h0 + h1 + h2 + h3;
                int suf = lsum; // inclusive suffix sum across lanes
#pragma unroll
                for (int d = 1; d < 64; d <<= 1) {
                    int v = __shfl_down(suf, d);
                    if (lane < 64 - d) suf += v;
                }
                const unsigned long long mm = __ballot(suf >= kk); // nonzero since cnt>=kk
                const int L = 63 - __clzll(mm);
                int dig = 0, kkn = 0;
                if (lane == L) {
                    int cum = suf - lsum;
                    const int hh[4] = {h0, h1, h2, h3};
#pragma unroll
                    for (int b = 3; b >= 0; --b) {
                        if (cum + hh[b] >= kk) { dig = lane * 4 + b; kkn = kk - cum; break; }
                        cum += hh[b];
                    }
                }
                dig = __shfl(dig, L);
                kk  = __shfl(kkn, L);
                prefix = (prefix << 8) | (unsigned int)dig;
            }
            if (lane == 0) { selT = prefix; selNeed = kk; }
        }
        __syncthreads(); // B3
        T = selT;
        need = selNeed;
    } else {
        // ---- exact fallback: full-block 4-pass histogram over all positives ----
        int kk = k;
        unsigned int prefix = 0;
        int t0 = 0;
        for (int p = 0; p < 4; ++p) {
            const int shift = 24 - 8 * p;
            hist[tid] = 0;
            if (tid == 0) sel_flag = 0;
            __syncthreads();
#pragma unroll
            for (int j = 0; j < EPT; ++j) {
                const unsigned int kj = key[j];
                if (kj != 0u && (p == 0 || (kj >> (shift + 8)) == prefix))
                    atomicAdd(&hist[(kj >> shift) & 255u], 1);
            }
            __syncthreads();
            if (tid < 64) {
                const int b0 = tid * 4;
                const int h0 = hist[b0 + 0], h1 = hist[b0 + 1];
                const int h2 = hist[b0 + 2], h3 = hist[b0 + 3];
                const int lsum = h0 + h1 + h2 + h3;
                int suf = lsum;
#pragma unroll
                for (int d = 1; d < 64; d <<= 1) {
                    int v = __shfl_down(suf, d);
                    if (lane < 64 - d) suf += v;
                }
                const unsigned long long mm = __ballot(suf >= kk);
                if (mm == 0ull) {
                    if (lane == 0) sel_flag = 1;
                } else {
                    const int L = 63 - __clzll(mm);
                    if (lane == L) {
                        int cum = suf - lsum;
                        const int hh[4] = {h0, h1, h2, h3};
#pragma unroll
                        for (int b = 3; b >= 0; --b) {
                            if (cum + hh[b] >= kk) { sel_digit = b0 + b; sel_kk = kk - cum; break; }
                            cum += hh[b];
                        }
                    }
                }
            }
            __syncthreads();
            if (sel_flag) { t0 = 1; break; }
            prefix = (prefix << 8) | (unsigned int)sel_digit;
            kk = sel_kk;
            __syncthreads(); // protect sel_* from next pass's re-init
        }
        if (t0) { T = 0u; need = 0; }
        else    { T = prefix; need = kk; }
    }

    // ---- stable rank of ==T elements in ascending column order ----
    int eqc = 0;
#pragma unroll
    for (int j = 0; j < EPT; ++j) eqc += (key[j] == T) ? 1 : 0;
    int einc = eqc;
#pragma unroll
    for (int d = 1; d < 64; d <<= 1) {
        int v = __shfl_up(einc, d);
        if (lane >= d) einc += v;
    }
    if (lane == 63) wtot[wid] = einc;
    __syncthreads(); // B4
    int rbase = 0;
    for (int w = 0; w < wid; ++w) rbase += wtot[w];
    int rr = rbase + (einc - eqc);

    // ---- emit (nontemporal: don't evict the L3-resident input) ----
    f32x4* __restrict__ ov = (f32x4*)(out + rowbase);
#pragma unroll
    for (int j = 0; j < 4; ++j) {
        f32x4 v;
#pragma unroll
        for (int c2 = 0; c2 < 4; ++c2) {
            const unsigned int kj = key[4 * j + c2];
            const bool eq = (kj == T);
            const bool keep = (kj > T) || (eq && rr < need);
            v[c2] = keep ? __uint_as_float(kj) : 0.0f;
            rr += eq ? 1 : 0;
        }
        __builtin_nontemporal_store(v, &ov[j]);
    }
}

extern "C" void kernel_launch(void* const* d_in, const int* in_sizes, int n_in,
                              void* d_out, int out_size, void* d_ws, size_t ws_size,
                              hipStream_t stream)
{
    const float* x    = (const float*)d_in[0];
    const int*   kptr = (const int*)d_in[1];
    float*       out  = (float*)d_out;
    const int rows = in_sizes[0] / ROW_LEN;
    topk_relu_kernel<<<rows, TPB, 0, stream>>>(x, kptr, out, rows);
}

// Round 6
// 127.459 us; speedup vs baseline: 2.3725x; 1.6866x over previous
//
#include <hip/hip_runtime.h>

// TopKActivation: out = relu(x) masked to the row-wise top-k of relu(x).
// [16384 x 4096] fp32, k=64. One 256-thread block per row, 16 elem/thread in
// registers; ~28 VGPRs -> HW runs 8 blocks/CU for TLP.
//
// LESSON LEDGER:
//  R3: persistent blocks + reg prefetch + LDS-only barriers -> 214us. Lost TLP.
//  R4: launch_bounds(256,8) -> 302us.
//  R5: NT stores -> WRITE_SIZE 523MB (1.95x ideal). NT stores on a layout
//      where each thread writes its 64B region as 4 separate 16B pieces
//      bypass L2 merging -> partial-line HBM write amplification. Every
//      NT-store round was >=214us; the plain-store round (R1) was 120.6us.
//  => plain stores only. Loads temporal (input L3-resident: FETCH 131MB).
//
// Threshold: candidates > 1.5f compacted into LDS (~274 of 4096 for N(0,1));
// wave 0 alone runs a 4x8-bit MSB radix select on the compacted list
// (positive floats order as uints). Only 4 block barriers on the fast path.
// Exact full-block fallback if the prefilter fails (cnt < k or cnt > CAP).
// Ties at threshold resolved stably (lowest column index) to match XLA top_k.

constexpr int ROW_LEN = 4096;
constexpr int TPB     = 256;
constexpr int EPT     = ROW_LEN / TPB; // 16
constexpr int CAP     = 512;
constexpr unsigned int KPRE_BITS = 0x3FC00000u; // bits of 1.5f

typedef float f32x4 __attribute__((ext_vector_type(4)));

__global__ __launch_bounds__(TPB, 4)
void topk_relu_kernel(const float* __restrict__ x, const int* __restrict__ kptr,
                      float* __restrict__ out, int rows)
{
    __shared__ unsigned int cand[CAP];
    __shared__ alignas(16) int hist[256];
    __shared__ int ccount;
    __shared__ unsigned int selT;
    __shared__ int selNeed;
    __shared__ int wtot[4];
    __shared__ int sel_digit, sel_kk, sel_flag;

    const int row = blockIdx.x;
    if (row >= rows) return;
    const int tid  = threadIdx.x;
    const int lane = tid & 63;
    const int wid  = tid >> 6;

    int k = *kptr;
    if (k > ROW_LEN) k = ROW_LEN;

    // ---- load row (blocked: thread t owns cols [16t,16t+16) => thread order == col order) ----
    const size_t rowbase = (size_t)row * ROW_LEN + (size_t)tid * EPT;
    const f32x4* __restrict__ xv = (const f32x4*)(x + rowbase);
    unsigned int key[EPT];
#pragma unroll
    for (int j = 0; j < 4; ++j) {
        f32x4 v = xv[j]; // temporal: input stays L3-resident across replays
#pragma unroll
        for (int c = 0; c < 4; ++c)
            key[4 * j + c] = __float_as_uint(fmaxf(v[c], 0.0f));
    }

    if (tid == 0) ccount = 0;
    __syncthreads(); // B1

    // ---- compact candidates > 1.5f into LDS ----
    int m = 0;
#pragma unroll
    for (int j = 0; j < EPT; ++j) m += (key[j] > KPRE_BITS) ? 1 : 0;
    int inc = m;
#pragma unroll
    for (int d = 1; d < 64; d <<= 1) {
        int v = __shfl_up(inc, d);
        if (lane >= d) inc += v;
    }
    const int excl = inc - m;
    const int wt   = __shfl(inc, 63);
    int wb = 0;
    if (lane == 0) wb = atomicAdd(&ccount, wt);
    wb = __shfl(wb, 0);
    int pos = wb + excl;
#pragma unroll
    for (int j = 0; j < EPT; ++j) {
        if (key[j] > KPRE_BITS) {
            if (pos < CAP) cand[pos] = key[j];
            ++pos;
        }
    }
    __syncthreads(); // B2
    const int cnt = ccount;

    unsigned int T;
    int need;

    if (cnt >= k && cnt <= CAP) {
        // ---- fast select: wave 0 only, no intra-pass barriers ----
        if (wid == 0) {
            unsigned int c[CAP / 64];
#pragma unroll
            for (int i = 0; i < CAP / 64; ++i) {
                const int idx = lane + 64 * i;
                c[i] = (idx < cnt) ? cand[idx] : 0u;
            }
            int kk = k;
            unsigned int prefix = 0;
#pragma unroll
            for (int p = 0; p < 4; ++p) {
                const int shift = 24 - 8 * p;
                ((int4*)hist)[lane] = make_int4(0, 0, 0, 0);
#pragma unroll
                for (int i = 0; i < CAP / 64; ++i) {
                    const int idx = lane + 64 * i;
                    const unsigned int ci = c[i];
                    if (idx < cnt && (p == 0 || (ci >> (shift + 8)) == prefix))
                        atomicAdd(&hist[(ci >> shift) & 255u], 1);
                }
                const int4 h = ((const int4*)hist)[lane];
                const int h0 = h.x, h1 = h.y, h2 = h.z, h3 = h.w;
                const int lsum = h0 + h1 + h2 + h3;
                int suf = lsum; // inclusive suffix sum across lanes
#pragma unroll
                for (int d = 1; d < 64; d <<= 1) {
                    int v = __shfl_down(suf, d);
                    if (lane < 64 - d) suf += v;
                }
                const unsigned long long mm = __ballot(suf >= kk); // nonzero since cnt>=kk
                const int L = 63 - __clzll(mm);
                int dig = 0, kkn = 0;
                if (lane == L) {
                    int cum = suf - lsum;
                    const int hh[4] = {h0, h1, h2, h3};
#pragma unroll
                    for (int b = 3; b >= 0; --b) {
                        if (cum + hh[b] >= kk) { dig = lane * 4 + b; kkn = kk - cum; break; }
                        cum += hh[b];
                    }
                }
                dig = __shfl(dig, L);
                kk  = __shfl(kkn, L);
                prefix = (prefix << 8) | (unsigned int)dig;
            }
            if (lane == 0) { selT = prefix; selNeed = kk; }
        }
        __syncthreads(); // B3
        T = selT;
        need = selNeed;
    } else {
        // ---- exact fallback: full-block 4-pass histogram over all positives ----
        int kk = k;
        unsigned int prefix = 0;
        int t0 = 0;
        for (int p = 0; p < 4; ++p) {
            const int shift = 24 - 8 * p;
            hist[tid] = 0;
            if (tid == 0) sel_flag = 0;
            __syncthreads();
#pragma unroll
            for (int j = 0; j < EPT; ++j) {
                const unsigned int kj = key[j];
                if (kj != 0u && (p == 0 || (kj >> (shift + 8)) == prefix))
                    atomicAdd(&hist[(kj >> shift) & 255u], 1);
            }
            __syncthreads();
            if (tid < 64) {
                const int b0 = tid * 4;
                const int h0 = hist[b0 + 0], h1 = hist[b0 + 1];
                const int h2 = hist[b0 + 2], h3 = hist[b0 + 3];
                const int lsum = h0 + h1 + h2 + h3;
                int suf = lsum;
#pragma unroll
                for (int d = 1; d < 64; d <<= 1) {
                    int v = __shfl_down(suf, d);
                    if (lane < 64 - d) suf += v;
                }
                const unsigned long long mm = __ballot(suf >= kk);
                if (mm == 0ull) {
                    if (lane == 0) sel_flag = 1;
                } else {
                    const int L = 63 - __clzll(mm);
                    if (lane == L) {
                        int cum = suf - lsum;
                        const int hh[4] = {h0, h1, h2, h3};
#pragma unroll
                        for (int b = 3; b >= 0; --b) {
                            if (cum + hh[b] >= kk) { sel_digit = b0 + b; sel_kk = kk - cum; break; }
                            cum += hh[b];
                        }
                    }
                }
            }
            __syncthreads();
            if (sel_flag) { t0 = 1; break; }
            prefix = (prefix << 8) | (unsigned int)sel_digit;
            kk = sel_kk;
            __syncthreads(); // protect sel_* from next pass's re-init
        }
        if (t0) { T = 0u; need = 0; }
        else    { T = prefix; need = kk; }
    }

    // ---- stable rank of ==T elements in ascending column order ----
    int eqc = 0;
#pragma unroll
    for (int j = 0; j < EPT; ++j) eqc += (key[j] == T) ? 1 : 0;
    int einc = eqc;
#pragma unroll
    for (int d = 1; d < 64; d <<= 1) {
        int v = __shfl_up(einc, d);
        if (lane >= d) einc += v;
    }
    if (lane == 63) wtot[wid] = einc;
    __syncthreads(); // B4
    int rbase = 0;
    for (int w = 0; w < wid; ++w) rbase += wtot[w];
    int rr = rbase + (einc - eqc);

    // ---- emit (PLAIN stores: L2 merges the 4x16B pieces per 64B region;
    //      NT stores measured 1.5-2.5x HBM write amplification) ----
    f32x4* __restrict__ ov = (f32x4*)(out + rowbase);
#pragma unroll
    for (int j = 0; j < 4; ++j) {
        f32x4 v;
#pragma unroll
        for (int c2 = 0; c2 < 4; ++c2) {
            const unsigned int kj = key[4 * j + c2];
            const bool eq = (kj == T);
            const bool keep = (kj > T) || (eq && rr < need);
            v[c2] = keep ? __uint_as_float(kj) : 0.0f;
            rr += eq ? 1 : 0;
        }
        ov[j] = v;
    }
}

extern "C" void kernel_launch(void* const* d_in, const int* in_sizes, int n_in,
                              void* d_out, int out_size, void* d_ws, size_t ws_size,
                              hipStream_t stream)
{
    const float* x    = (const float*)d_in[0];
    const int*   kptr = (const int*)d_in[1];
    float*       out  = (float*)d_out;
    const int rows = in_sizes[0] / ROW_LEN;
    topk_relu_kernel<<<rows, TPB, 0, stream>>>(x, kptr, out, rows);
}

// Round 7
// 100.861 us; speedup vs baseline: 2.9981x; 1.2637x over previous
//
#include <hip/hip_runtime.h>

// TopKActivation: out = relu(x) masked to the row-wise top-k of relu(x).
// [16384 x 4096] fp32, k=64. One 256-thread block per row.
//
// LESSON LEDGER:
//  R3: persistent blocks + reg prefetch + LDS-only barriers -> 214us (lost TLP).
//  R4: launch_bounds(256,8) -> 302us (spill-ish write amplification).
//  R5: NT stores -> WRITE_SIZE 523MB = 1.95x ideal; partial-line HBM writes.
//  R6: plain stores -> 127.5us. Confirmed NT stores were the poison.
//  R7 (this): blocked layout (thread t owns cols [16t,16t+16)) gives every
//      vector load/store a 64B lane stride -> 64 cache lines touched per wave
//      instruction instead of 16 -> 4x memory transactions. Kernel ran at
//      3.2 TB/s with VALUBusy 15%: transaction-rate-bound, not BW/VALU-bound.
//      Switch to interleaved layout: thread t, chunk j owns cols j*1024+4t..+3
//      (lane stride 16B = fully coalesced, 1KiB per wave instruction).
//
// Threshold: candidates > 1.5f compacted into LDS (~274 of 4096 for N(0,1));
// wave 0 alone runs a 4x8-bit MSB radix select on the compacted list
// (positive floats order as uints). Exact full-block fallback if prefilter
// fails (cnt < k or cnt > CAP). Ties at T resolved stably (lowest column
// first) to match XLA top_k: under the interleaved layout, column order ==
// (j, tid, c) lexicographic, handled by a packed 4x16-bit block scan of
// per-(thread,j) eq-counts.

constexpr int ROW_LEN = 4096;
constexpr int TPB     = 256;
constexpr int CAP     = 512;
constexpr unsigned int KPRE_BITS = 0x3FC00000u; // bits of 1.5f

typedef float f32x4 __attribute__((ext_vector_type(4)));

__global__ __launch_bounds__(TPB, 4)
void topk_relu_kernel(const float* __restrict__ x, const int* __restrict__ kptr,
                      float* __restrict__ out, int rows)
{
    __shared__ unsigned int cand[CAP];
    __shared__ alignas(16) int hist[256];
    __shared__ int ccount;
    __shared__ unsigned int selT;
    __shared__ int selNeed;
    __shared__ unsigned long long wtot64[4];
    __shared__ int wtot[4];
    __shared__ int sel_digit, sel_kk, sel_flag;

    const int row = blockIdx.x;
    if (row >= rows) return;
    const int tid  = threadIdx.x;
    const int lane = tid & 63;
    const int wid  = tid >> 6;

    int k = *kptr;
    if (k > ROW_LEN) k = ROW_LEN;

    // ---- load row, interleaved: thread t chunk j -> cols j*1024 + 4t + c ----
    // Lane-to-lane stride 16B: one wave load = 1KiB contiguous (coalesced).
    const float* __restrict__ xrow = x + (size_t)row * ROW_LEN;
    unsigned int key[16];
#pragma unroll
    for (int j = 0; j < 4; ++j) {
        f32x4 v = *(const f32x4*)(xrow + j * 1024 + tid * 4);
#pragma unroll
        for (int c = 0; c < 4; ++c)
            key[4 * j + c] = __float_as_uint(fmaxf(v[c], 0.0f));
    }

    if (tid == 0) ccount = 0;
    __syncthreads(); // B1

    // ---- compact candidates > 1.5f into LDS (order-independent) ----
    int m = 0;
#pragma unroll
    for (int j = 0; j < 16; ++j) m += (key[j] > KPRE_BITS) ? 1 : 0;
    int inc = m;
#pragma unroll
    for (int d = 1; d < 64; d <<= 1) {
        int v = __shfl_up(inc, d);
        if (lane >= d) inc += v;
    }
    const int excl = inc - m;
    const int wt   = __shfl(inc, 63);
    int wb = 0;
    if (lane == 0) wb = atomicAdd(&ccount, wt);
    wb = __shfl(wb, 0);
    int pos = wb + excl;
#pragma unroll
    for (int j = 0; j < 16; ++j) {
        if (key[j] > KPRE_BITS) {
            if (pos < CAP) cand[pos] = key[j];
            ++pos;
        }
    }
    __syncthreads(); // B2
    const int cnt = ccount;

    unsigned int T;
    int need;

    if (cnt >= k && cnt <= CAP) {
        // ---- fast select: wave 0 only, no intra-pass barriers ----
        if (wid == 0) {
            unsigned int c[CAP / 64];
#pragma unroll
            for (int i = 0; i < CAP / 64; ++i) {
                const int idx = lane + 64 * i;
                c[i] = (idx < cnt) ? cand[idx] : 0u;
            }
            int kk = k;
            unsigned int prefix = 0;
#pragma unroll
            for (int p = 0; p < 4; ++p) {
                const int shift = 24 - 8 * p;
                ((int4*)hist)[lane] = make_int4(0, 0, 0, 0);
#pragma unroll
                for (int i = 0; i < CAP / 64; ++i) {
                    const int idx = lane + 64 * i;
                    const unsigned int ci = c[i];
                    if (idx < cnt && (p == 0 || (ci >> (shift + 8)) == prefix))
                        atomicAdd(&hist[(ci >> shift) & 255u], 1);
                }
                const int4 h = ((const int4*)hist)[lane];
                const int h0 = h.x, h1 = h.y, h2 = h.z, h3 = h.w;
                const int lsum = h0 + h1 + h2 + h3;
                int suf = lsum; // inclusive suffix sum across lanes
#pragma unroll
                for (int d = 1; d < 64; d <<= 1) {
                    int v = __shfl_down(suf, d);
                    if (lane < 64 - d) suf += v;
                }
                const unsigned long long mm = __ballot(suf >= kk); // nonzero since cnt>=kk
                const int L = 63 - __clzll(mm);
                int dig = 0, kkn = 0;
                if (lane == L) {
                    int cum = suf - lsum;
                    const int hh[4] = {h0, h1, h2, h3};
#pragma unroll
                    for (int b = 3; b >= 0; --b) {
                        if (cum + hh[b] >= kk) { dig = lane * 4 + b; kkn = kk - cum; break; }
                        cum += hh[b];
                    }
                }
                dig = __shfl(dig, L);
                kk  = __shfl(kkn, L);
                prefix = (prefix << 8) | (unsigned int)dig;
            }
            if (lane == 0) { selT = prefix; selNeed = kk; }
        }
        __syncthreads(); // B3
        T = selT;
        need = selNeed;
    } else {
        // ---- exact fallback: full-block 4-pass histogram over all positives ----
        int kk = k;
        unsigned int prefix = 0;
        int t0 = 0;
        for (int p = 0; p < 4; ++p) {
            const int shift = 24 - 8 * p;
            hist[tid] = 0;
            if (tid == 0) sel_flag = 0;
            __syncthreads();
#pragma unroll
            for (int j = 0; j < 16; ++j) {
                const unsigned int kj = key[j];
                if (kj != 0u && (p == 0 || (kj >> (shift + 8)) == prefix))
                    atomicAdd(&hist[(kj >> shift) & 255u], 1);
            }
            __syncthreads();
            if (tid < 64) {
                const int b0 = tid * 4;
                const int h0 = hist[b0 + 0], h1 = hist[b0 + 1];
                const int h2 = hist[b0 + 2], h3 = hist[b0 + 3];
                const int lsum = h0 + h1 + h2 + h3;
                int suf = lsum;
#pragma unroll
                for (int d = 1; d < 64; d <<= 1) {
                    int v = __shfl_down(suf, d);
                    if (lane < 64 - d) suf += v;
                }
                const unsigned long long mm = __ballot(suf >= kk);
                if (mm == 0ull) {
                    if (lane == 0) sel_flag = 1;
                } else {
                    const int L = 63 - __clzll(mm);
                    if (lane == L) {
                        int cum = suf - lsum;
                        const int hh[4] = {h0, h1, h2, h3};
#pragma unroll
                        for (int b = 3; b >= 0; --b) {
                            if (cum + hh[b] >= kk) { sel_digit = b0 + b; sel_kk = kk - cum; break; }
                            cum += hh[b];
                        }
                    }
                }
            }
            __syncthreads();
            if (sel_flag) { t0 = 1; break; }
            prefix = (prefix << 8) | (unsigned int)sel_digit;
            kk = sel_kk;
            __syncthreads(); // protect sel_* from next pass's re-init
        }
        if (t0) { T = 0u; need = 0; }
        else    { T = prefix; need = kk; }
    }

    // ---- stable rank of ==T elements in column order ----
    // Column order == lexicographic (j, tid, c). Pack per-(thread,j) eq-counts
    // into 4x16-bit lanes of a u64; one block scan yields per-group thread
    // prefixes AND group totals. Max per lane 4096 < 65536: no carry.
    unsigned long long packed = 0ull;
#pragma unroll
    for (int j = 0; j < 4; ++j) {
        int e = 0;
#pragma unroll
        for (int c = 0; c < 4; ++c) e += (key[4 * j + c] == T) ? 1 : 0;
        packed |= (unsigned long long)e << (16 * j);
    }
    unsigned long long incp = packed;
#pragma unroll
    for (int d = 1; d < 64; d <<= 1) {
        unsigned long long v = __shfl_up(incp, d);
        if (lane >= d) incp += v;
    }
    if (lane == 63) wtot64[wid] = incp;
    __syncthreads(); // B4
    unsigned long long base = 0ull;
    for (int w = 0; w < wid; ++w) base += wtot64[w];
    const unsigned long long exclp = base + incp - packed; // exclusive prefix per group
    const unsigned long long tot = wtot64[0] + wtot64[1] + wtot64[2] + wtot64[3];
    int S[4];
    S[0] = 0;
    S[1] = (int)(tot & 0xFFFFull);
    S[2] = S[1] + (int)((tot >> 16) & 0xFFFFull);
    S[3] = S[2] + (int)((tot >> 32) & 0xFFFFull);

    // ---- emit, coalesced ----
    float* __restrict__ orow = out + (size_t)row * ROW_LEN;
#pragma unroll
    for (int j = 0; j < 4; ++j) {
        int rr = S[j] + (int)((exclp >> (16 * j)) & 0xFFFFull);
        f32x4 v;
#pragma unroll
        for (int c2 = 0; c2 < 4; ++c2) {
            const unsigned int kj = key[4 * j + c2];
            const bool eq = (kj == T);
            const bool keep = (kj > T) || (eq && rr < need);
            v[c2] = keep ? __uint_as_float(kj) : 0.0f;
            rr += eq ? 1 : 0;
        }
        *(f32x4*)(orow + j * 1024 + tid * 4) = v;
    }
}

extern "C" void kernel_launch(void* const* d_in, const int* in_sizes, int n_in,
                              void* d_out, int out_size, void* d_ws, size_t ws_size,
                              hipStream_t stream)
{
    const float* x    = (const float*)d_in[0];
    const int*   kptr = (const int*)d_in[1];
    float*       out  = (float*)d_out;
    const int rows = in_sizes[0] / ROW_LEN;
    topk_relu_kernel<<<rows, TPB, 0, stream>>>(x, kptr, out, rows);
}